// Round 5
// baseline (4377.262 us; speedup 1.0000x reference)
//
#include <hip/hip_runtime.h>
#include <math.h>

#define NN 65536
#define KNB 16
#define THREADS 256
#define UNR 8
#define NBLOCKS (NN / THREADS)

// Packed-key exponent bias: keeps every live f64 key a NORMAL double
// (no subnormal flush hazard on v_min_f64/v_max_f64), order-preserving.
// Assumes d2 < ~3e38 (bits < 0x7F600000) — guaranteed for sane inputs.
#define KEY_BIAS 0x00800000u

// ---------------------------------------------------------------------------
// Kernel 1: prep — s = x@Ws^T+bs, h = x@Wh^T+bh, candidate record (-2s, |s|^2)
// ---------------------------------------------------------------------------
__global__ __launch_bounds__(THREADS) void prep_kernel(
    const float* __restrict__ x,
    const float* __restrict__ Ws, const float* __restrict__ bs,
    const float* __restrict__ Wh, const float* __restrict__ bh,
    float4* __restrict__ cand, float* __restrict__ h)
{
    const int i = blockIdx.x * THREADS + threadIdx.x;
    const float4 xi = reinterpret_cast<const float4*>(x)[i];
    const float sx = fmaf(Ws[0], xi.x, fmaf(Ws[1], xi.y, fmaf(Ws[2],  xi.z, fmaf(Ws[3],  xi.w, bs[0]))));
    const float sy = fmaf(Ws[4], xi.x, fmaf(Ws[5], xi.y, fmaf(Ws[6],  xi.z, fmaf(Ws[7],  xi.w, bs[1]))));
    const float sz = fmaf(Ws[8], xi.x, fmaf(Ws[9], xi.y, fmaf(Ws[10], xi.z, fmaf(Ws[11], xi.w, bs[2]))));
    const float hh = fmaf(Wh[0], xi.x, fmaf(Wh[1], xi.y, fmaf(Wh[2],  xi.z, fmaf(Wh[3],  xi.w, bh[0]))));
    const float pn = fmaf(sx, sx, fmaf(sy, sy, sz * sz));
    cand[i] = make_float4(-2.0f * sx, -2.0f * sy, -2.0f * sz, pn);
    h[i] = hh;
}

// ---------------------------------------------------------------------------
// Kernel 2: brute-force kNN scan + fused GravNet epilogue.
//   dd(c) = |p_c|^2 - 2 p_c . q_i        (= d2 - |q_i|^2, order-preserving)
//   thr   = worst_kept_d2 - |q_i|^2      (compare in dd-space: no add/pair)
//   top-16 as f64 bit-pack ((d2_bits+BIAS)<<32 | idx): f64 numeric order ==
//   lexicographic (d2, idx) -> stable top_k ties; bias keeps keys normal
//   doubles (self-pair d2 can round to +/-eps; unbiased would pack a
//   subnormal whose idx payload denorm-flushing min/max would destroy).
//   Negative-rounded d2 packs to a negative normal double -> sorts first,
//   exactly where d2~0 belongs.
//   Block-of-8 min-filter: one branch per 8 candidates.
//   Median-split insertion: keys land at uniform rank; P=1/2 they only
//   ripple slots 8..15 (halves the f64 chain).
//   4-buffer rotating prefetch: issue-to-use distance = 4 blocks (~280 cy)
//   > L2 hit latency (~200 cy); 1 wave/SIMD so registers are free.
//   Deterministic pooling: per-block partials to ws; no global atomics.
// ---------------------------------------------------------------------------
__global__ __launch_bounds__(THREADS, 1) void gravnet_kernel(
    const float* __restrict__ x,
    const float4* __restrict__ cand,
    const float* __restrict__ h,
    const float* __restrict__ Wout, const float* __restrict__ bout,
    float* __restrict__ partials)          // [NBLOCKS][64]
{
    const int i = blockIdx.x * THREADS + threadIdx.x;

    const float4 q = cand[i];          // (-2*s_i, |s_i|^2)
    const float six = -0.5f * q.x;     // s_i (bit-exact: *-2 then *-0.5)
    const float siy = -0.5f * q.y;
    const float siz = -0.5f * q.z;
    const float qn  = q.w;             // |s_i|^2

    double slot[KNB];
    // INIT: huge NORMAL double (exp=0x7FE), sorts after every real key.
    const double INIT = __longlong_as_double(0x7FE00000FFFFFFFFLL);
#pragma unroll
    for (int j = 0; j < KNB; ++j) slot[j] = INIT;
    // thr starts effectively +inf: unbias(0x7FE00000) = 0x7F600000 ~ 2.98e38
    float thr = __uint_as_float(0x7FE00000u - KEY_BIAS);

    auto process = [&](const float4* P, int cbase) {
        float dd[UNR];
#pragma unroll
        for (int j = 0; j < UNR; ++j)
            dd[j] = fmaf(P[j].x, six, fmaf(P[j].y, siy, fmaf(P[j].z, siz, P[j].w)));
        // associativity written to encourage v_min3_f32 folding
        const float bmin = fminf(
            fminf(fminf(dd[0], dd[1]), dd[2]),
            fminf(fminf(fminf(dd[3], dd[4]), dd[5]), fminf(dd[6], dd[7])));
        if (__builtin_expect(bmin < thr, 0)) {
#pragma unroll
            for (int j = 0; j < UNR; ++j) {
                if (dd[j] < thr) {
                    const float d2 = dd[j] + qn;
                    const unsigned long long ub =
                        ((unsigned long long)(__float_as_uint(d2) + KEY_BIAS) << 32)
                        | (unsigned)(cbase + j);
                    double run = __longlong_as_double((long long)ub);
                    if (run > slot[KNB / 2 - 1]) {
                        // upper half only: slots 0..7 provably unchanged
#pragma unroll
                        for (int t = KNB / 2; t < KNB; ++t) {
                            const double lo = fmin(slot[t], run);
                            run = fmax(slot[t], run);
                            slot[t] = lo;
                        }
                    } else {
#pragma unroll
                        for (int t = 0; t < KNB; ++t) {
                            const double lo = fmin(slot[t], run);
                            run = fmax(slot[t], run);
                            slot[t] = lo;
                        }
                    }
                    thr = __uint_as_float(
                              (unsigned)((unsigned long long)
                                  __double_as_longlong(slot[KNB - 1]) >> 32)
                              - KEY_BIAS) - qn;
                }
            }
        }
    };

    auto reload = [&](float4* P, int eb) {
        const int s = eb & (NN - 1);   // wraps to start on final iterations
#pragma unroll
        for (int j = 0; j < UNR; ++j) P[j] = cand[s + j];
    };

    float4 A[UNR], B[UNR], C[UNR], D[UNR];
    reload(A, 0); reload(B, UNR); reload(C, 2 * UNR); reload(D, 3 * UNR);

#pragma unroll 1
    for (int base = 0; base < NN; base += 4 * UNR) {
        process(A, base);            reload(A, base + 4 * UNR);
        process(B, base + UNR);      reload(B, base + 5 * UNR);
        process(C, base + 2 * UNR);  reload(C, base + 6 * UNR);
        process(D, base + 3 * UNR);  reload(D, base + 7 * UNR);
    }

    // Epilogue: exact d2 (reference's subtract-form rounding), weights, agg.
    // Slots ascend in (d2, idx) == top_k return order, so f32 summation
    // order matches the reference's mean reduction.
    float msum = 0.0f;
    float mmax = -INFINITY;
#pragma unroll
    for (int j = 0; j < KNB; ++j) {
        const unsigned long long b =
            (unsigned long long)__double_as_longlong(slot[j]);
        const int idx = (int)(unsigned)(b & 0xFFFFFFFFu);
        const float4 p = cand[idx];
        const float dx = six - (-0.5f * p.x);
        const float dy = siy - (-0.5f * p.y);
        const float dz = siz - (-0.5f * p.z);
        const float d2 = fmaf(dx, dx, fmaf(dy, dy, dz * dz));
        const float w  = expf(-10.0f * d2);
        const float m  = h[idx] * w;
        msum += m;
        mmax = fmaxf(mmax, m);
    }
    const float mmean = msum * (1.0f / 16.0f);   // *2^-4 == /16 exactly

    // conv = [x_i, mean, max] @ Wout^T + bout ; elu ; block-level reduction
    const float4 xi = reinterpret_cast<const float4*>(x)[i];
    const float in0 = xi.x, in1 = xi.y, in2 = xi.z, in3 = xi.w;
    const float in4 = mmean, in5 = mmax;
    const int lane = threadIdx.x & 63;
    const int wid  = threadIdx.x >> 6;

    __shared__ float bsum[4][64];

    for (int o = 0; o < 64; ++o) {
        const float* wr = Wout + o * 6;
        float a = fmaf(wr[0], in0, fmaf(wr[1], in1, fmaf(wr[2], in2,
                  fmaf(wr[3], in3, fmaf(wr[4], in4, fmaf(wr[5], in5, bout[o]))))));
        a = (a > 0.0f) ? a : expm1f(a);
        a += __shfl_xor(a, 32);
        a += __shfl_xor(a, 16);
        a += __shfl_xor(a, 8);
        a += __shfl_xor(a, 4);
        a += __shfl_xor(a, 2);
        a += __shfl_xor(a, 1);
        if (lane == 0) bsum[wid][o] = a;
    }
    __syncthreads();
    if (threadIdx.x < 64) {
        const int o = threadIdx.x;
        partials[blockIdx.x * 64 + o] =
            (bsum[0][o] + bsum[1][o]) + (bsum[2][o] + bsum[3][o]);
    }
}

// ---------------------------------------------------------------------------
// Kernel 3: deterministic fixed-order reduction of block partials, then
// out = pooled @ Wfin^T + bfin.  (No atomics anywhere -> replay-stable.)
// ---------------------------------------------------------------------------
__global__ void final_kernel(const float* __restrict__ partials,  // [NBLOCKS][64]
                             const float* __restrict__ Wfin,
                             const float* __restrict__ bfin,
                             float* __restrict__ out)
{
    const int t = threadIdx.x;  // 64 threads, one channel each
    double acc = 0.0;
#pragma unroll 8
    for (int b = 0; b < NBLOCKS; ++b)
        acc += (double)partials[b * 64 + t];   // coalesced across lanes
    double v = acc * (double)Wfin[t];
    v += __shfl_xor(v, 32);
    v += __shfl_xor(v, 16);
    v += __shfl_xor(v, 8);
    v += __shfl_xor(v, 4);
    v += __shfl_xor(v, 2);
    v += __shfl_xor(v, 1);
    if (t == 0) out[0] = (float)(v + (double)bfin[0]);
}

extern "C" void kernel_launch(void* const* d_in, const int* in_sizes, int n_in,
                              void* d_out, int out_size, void* d_ws, size_t ws_size,
                              hipStream_t stream)
{
    const float* x    = (const float*)d_in[0];
    const float* Ws   = (const float*)d_in[1];
    const float* bs   = (const float*)d_in[2];
    const float* Wh   = (const float*)d_in[3];
    const float* bh   = (const float*)d_in[4];
    const float* Wout = (const float*)d_in[5];
    const float* bout = (const float*)d_in[6];
    const float* Wfin = (const float*)d_in[7];
    const float* bfin = (const float*)d_in[8];
    float* out = (float*)d_out;

    char* ws = (char*)d_ws;
    float4* cand     = (float4*)ws;                               // 1 MB
    float*  h        = (float*)(ws + (size_t)NN * 16);            // 256 KB
    float*  partials = (float*)(ws + (size_t)NN * 16 + (size_t)NN * 4);  // 64 KB

    prep_kernel<<<NBLOCKS, THREADS, 0, stream>>>(x, Ws, bs, Wh, bh, cand, h);
    gravnet_kernel<<<NBLOCKS, THREADS, 0, stream>>>(x, cand, h, Wout, bout, partials);
    final_kernel<<<1, 64, 0, stream>>>(partials, Wfin, bfin, out);
}